// Round 18
// baseline (258.233 us; speedup 1.0000x reference)
//
#include <hip/hip_runtime.h>
#include <math.h>

#define D 128
#define EPB 4096          // edges per block for hist/scatter
#define MAXNB 800         // LDS histogram capacity (NB = ceil(N/128) = 782)

typedef unsigned long long ull;
typedef unsigned short ushort_t;
typedef __attribute__((ext_vector_type(8))) short bf16x8;
typedef __attribute__((ext_vector_type(4))) float f32x4;

__device__ __forceinline__ float bf_lo(unsigned u) { return __uint_as_float(u << 16); }
__device__ __forceinline__ float bf_hi(unsigned u) { return __uint_as_float(u & 0xffff0000u); }
__device__ __forceinline__ unsigned bpack(float a, float b) {  // RNE bf16x2
  unsigned ua = __float_as_uint(a), ub = __float_as_uint(b);
  ua += 0x7fff + ((ua >> 16) & 1);
  ub += 0x7fff + ((ub >> 16) & 1);
  return (ua >> 16) | (ub & 0xffff0000u);
}
__device__ __forceinline__ ushort_t bh16(float a) {  // RNE bf16
  unsigned ua = __float_as_uint(a);
  ua += 0x7fff + ((ua >> 16) & 1);
  return (ushort_t)(ua >> 16);
}

// ---- hist level-1 (col>>7) with LDS atomics; prep (x cast + W bf16 hi/lo split) in tail blocks ----
__global__ __launch_bounds__(256) void k_h1(const int* __restrict__ col, int E, int B1, int B1pad,
                                            int* __restrict__ gh, int NB,
                                            const float2* __restrict__ x2, unsigned* __restrict__ xb, int n64,
                                            const float* __restrict__ W1, const float* __restrict__ W2,
                                            ushort_t* __restrict__ Whi1, ushort_t* __restrict__ Wlo1,
                                            ushort_t* __restrict__ Whi2, ushort_t* __restrict__ Wlo2) {
  int b = blockIdx.x, t = threadIdx.x;
  if (b < B1) {
    __shared__ int h[MAXNB];
    for (int i = t; i < NB; i += 256) h[i] = 0;
    __syncthreads();
    int e0 = b * EPB, e1 = min(E, e0 + EPB);
    for (int e = e0 + t; e < e1; e += 256) atomicAdd(&h[col[e] >> 7], 1);
    __syncthreads();
    for (int i = t; i < NB; i += 256) gh[i * B1pad + b] = h[i];
    return;
  }
  int idx = (b - B1) * 256 + t;
  if (idx < n64) { float2 v = x2[idx]; xb[idx] = bpack(v.x, v.y); return; }
  int j = idx - n64;
  if (j >= 2 * D * D) return;
  const float* W = (j < D * D) ? W1 : W2;
  ushort_t* Hh = (j < D * D) ? Whi1 : Whi2;
  ushort_t* Hl = (j < D * D) ? Wlo1 : Wlo2;
  int k = j & (D * D - 1);
  float w = W[k];
  ushort_t hh = bh16(w);
  Hh[k] = hh;
  Hl[k] = bh16(w - __uint_as_float((unsigned)hh << 16));
}

// ---- per-bin scan across blocks (B1 <= 512): gh[bin][b] -> excl prefix; binTotal[bin] = sum ----
__global__ __launch_bounds__(512) void k_hscan(int* __restrict__ gh, int* __restrict__ binTotal,
                                               int B1, int B1pad) {
  __shared__ int wsum[8];
  int bin = blockIdx.x, t = threadIdx.x;
  int v = (t < B1) ? gh[bin * B1pad + t] : 0;
  int lane = t & 63, wid = t >> 6;
  int x = v;
  #pragma unroll
  for (int d = 1; d < 64; d <<= 1) { int y = __shfl_up(x, d, 64); if (lane >= d) x += y; }
  if (lane == 63) wsum[wid] = x;
  __syncthreads();
  int woff = 0;
  for (int w = 0; w < wid; ++w) woff += wsum[w];
  if (t < B1) gh[bin * B1pad + t] = woff + x - v;
  if (t == 511) binTotal[bin] = woff + x;   // last lane of last wave: inclusive total
}

// ---------------- block exclusive scan helper (256 threads) ----------------
__device__ __forceinline__ int block_excl_scan(int v, int t, int* wsum, int* total) {
  int lane = t & 63, wid = t >> 6;
  int x = v;
  #pragma unroll
  for (int d = 1; d < 64; d <<= 1) {
    int y = __shfl_up(x, d, 64);
    if (lane >= d) x += y;
  }
  if (lane == 63) wsum[wid] = x;
  __syncthreads();
  int woff = 0;
  for (int w = 0; w < wid; ++w) woff += wsum[w];
  if (total) { int tot = 0; for (int w = 0; w < 4; ++w) tot += wsum[w]; *total = tot; }
  return woff + x - v;
}

// ---- scatter: LDS counting-sort per block, coalesced packed-ull output ----
__global__ __launch_bounds__(256) void k_scatter(const int* __restrict__ row, const int* __restrict__ col,
                                                 const float* __restrict__ ew,
                                                 const int* __restrict__ gh, const int* __restrict__ binTotal,
                                                 int B1pad, int NB,
                                                 ull* __restrict__ a_e, int E) {
  __shared__ ull recs[EPB];
  __shared__ int hist[MAXNB];   // becomes exclusive pfx in place
  __shared__ int cur[MAXNB];
  __shared__ int wb[MAXNB];
  __shared__ int bbase[MAXNB];
  __shared__ int wsum[4];
  int b = blockIdx.x, t = threadIdx.x;
  for (int i = t; i < NB; i += 256) { hist[i] = 0; cur[i] = 0; }
  __syncthreads();
  int e0 = b * EPB;
  int cnt = min(E - e0, EPB);
  ull v[16];
  #pragma unroll
  for (int k = 0; k < 16; ++k) {
    int idx = t + k * 256;
    v[k] = 0;
    if (idx < cnt) {
      int e = e0 + idx;
      int c = col[e];
      unsigned q = __float2uint_rn(ew[e] * 32767.0f);
      if (q > 32767u) q = 32767u;
      unsigned hi = ((unsigned)c << 15) | q;
      v[k] = ((ull)hi << 32) | (unsigned)row[e];
      atomicAdd(&hist[hi >> 22], 1);
    }
  }
  __syncthreads();
  int base = t * 4;
  // scan #A: binTotal -> bbase (exclusive bin bases)
  int bt[4]; int sb = 0;
  #pragma unroll
  for (int u = 0; u < 4; ++u) { bt[u] = (base + u < NB) ? binTotal[base + u] : 0; sb += bt[u]; }
  int exb = block_excl_scan(sb, t, wsum, nullptr);
  {
    int run = exb;
    #pragma unroll
    for (int u = 0; u < 4; ++u) { if (base + u < NB) bbase[base + u] = run; run += bt[u]; }
  }
  __syncthreads();
  // scan #B: hist -> exclusive pfx in place; wb = bbase + gh - pfx
  int hv[4];
  #pragma unroll
  for (int u = 0; u < 4; ++u) hv[u] = (base + u < NB) ? hist[base + u] : 0;
  int s = hv[0] + hv[1] + hv[2] + hv[3];
  int excl = block_excl_scan(s, t, wsum, nullptr);
  int run = excl;
  #pragma unroll
  for (int u = 0; u < 4; ++u) {
    if (base + u < NB) {
      hist[base + u] = run;
      wb[base + u] = bbase[base + u] + gh[(base + u) * B1pad + b] - run;
    }
    run += hv[u];
  }
  __syncthreads();
  #pragma unroll
  for (int k = 0; k < 16; ++k) {
    if (t + k * 256 < cnt) {
      unsigned bkt = (unsigned)(v[k] >> 54);
      int idx = hist[bkt] + atomicAdd(&cur[bkt], 1);
      recs[idx] = v[k];
    }
  }
  __syncthreads();
  for (int i = t; i < cnt; i += 256) {
    ull r = recs[i];
    a_e[wb[(unsigned)(r >> 54)] + i] = r;
  }
}

// ---- level-2: per-bucket 128-bin counting sort; emits offs, dinv, dest-sorted (r<<15|ew_q15) ----
__global__ __launch_bounds__(256) void k_bucket(const ull* __restrict__ a_e,
                                                const int* __restrict__ binTotal,
                                                int* __restrict__ offs, float* __restrict__ dinv,
                                                unsigned* __restrict__ sorted2, int N, int E, int NB) {
  __shared__ int hist[128];
  __shared__ float wdeg[128];
  __shared__ int pfx[128];
  __shared__ int cur[128];
  __shared__ int wred[4];
  __shared__ int s0sh;
  int bin = blockIdx.x, t = threadIdx.x;
  if (t < 128) { hist[t] = 0; wdeg[t] = 0.f; cur[t] = 0; }
  // masked block-reduce: s0 = sum_{j<bin} binTotal[j]
  int part = 0;
  for (int j = t; j < NB; j += 256) if (j < bin) part += binTotal[j];
  #pragma unroll
  for (int d = 32; d >= 1; d >>= 1) part += __shfl_xor(part, d, 64);
  if ((t & 63) == 0) wred[t >> 6] = part;
  __syncthreads();
  if (t == 0) s0sh = wred[0] + wred[1] + wred[2] + wred[3];
  if (t == 0 && bin == 0) offs[N] = E;
  __syncthreads();
  int s0 = s0sh;
  int s1 = s0 + binTotal[bin];
  for (int i = s0 + t; i < s1; i += 256) {
    unsigned hi = (unsigned)(a_e[i] >> 32);
    int lc = (hi >> 15) & 127;
    atomicAdd(&hist[lc], 1);
    atomicAdd(&wdeg[lc], (float)(hi & 32767u) * (1.0f / 32767.0f));
  }
  __syncthreads();
  if (t == 0) { int run = 0; for (int i = 0; i < 128; ++i) { pfx[i] = run; run += hist[i]; } }
  __syncthreads();
  int c0 = bin << 7;
  if (t < 128 && c0 + t < N) {
    offs[c0 + t] = s0 + pfx[t];
    dinv[c0 + t] = rsqrtf(wdeg[t] + 1.0f);
  }
  for (int i = s0 + t; i < s1; i += 256) {
    ull v = a_e[i];
    unsigned hi = (unsigned)(v >> 32);
    int lc = (hi >> 15) & 127;
    int pos = s0 + pfx[lc] + atomicAdd(&cur[lc], 1);
    sorted2[pos] = ((unsigned)v << 15) | (hi & 32767u);   // r<<15 | ew_q15
  }
}

// ---- FUSED agg+GEMM: block = 16 nodes; 4 waves x 4 sequential nodes (R8 agg body),
//      barrier, then 16x128 GEMM from LDS with bf16 hi/lo W (B in regs).
// TANH: out bf16. else: out f32 + bf16 skip. Numerics identical to unfused chain.
template<int TANH, int SKIP>
__global__ __launch_bounds__(256) void k_aggmm(const unsigned* __restrict__ H2,
                                               const unsigned* __restrict__ elist,
                                               const int* __restrict__ offs, const float* __restrict__ dinv,
                                               const ushort_t* __restrict__ Whi,
                                               const ushort_t* __restrict__ Wlo,
                                               const float* __restrict__ bias,
                                               const ushort_t* __restrict__ skipb,
                                               void* __restrict__ outv, int N) {
  __shared__ ushort_t sRow[16][136];   // 272B row stride -> <=2-way LDS bank aliasing (free)
  int t = threadIdx.x;
  int wave = t >> 6, lane = t & 63;
  int q = lane >> 4;            // edge slot 0..3 (agg) / k-group (gemm)
  int fi = lane & 15;           // uint4 slot (agg) / A-row & col offset (gemm)
  int blk = blockIdx.x;

  // ---- stage 1: aggregate 4 nodes per wave into LDS ----
  for (int sub = 0; sub < 4; ++sub) {
    int row = wave * 4 + sub;
    int c = blk * 16 + row;
    if (c < N) {
      int start = offs[c];
      int m = offs[c + 1] - start;
      float dv = dinv[c];
      float dcs = dv * (1.0f / 32767.0f);
      float a0 = 0.f, a1 = 0.f, a2 = 0.f, a3 = 0.f, a4 = 0.f, a5 = 0.f, a6 = 0.f, a7 = 0.f;
      for (int base = 0; base < m; base += 64) {
        int chunk = min(64, m - base);
        unsigned rec = (lane < chunk) ? elist[start + base + lane] : 0u;  // pad: row0, w=0
        int iters = (chunk + 3) >> 2;
        int i = 0;
        for (; i + 4 <= iters; i += 4) {
          unsigned e0 = __shfl(rec, 4 * i + q, 64);
          unsigned e1 = __shfl(rec, 4 * i + 4 + q, 64);
          unsigned e2 = __shfl(rec, 4 * i + 8 + q, 64);
          unsigned e3 = __shfl(rec, 4 * i + 12 + q, 64);
          uint4 u0 = *(const uint4*)&H2[(size_t)(e0 >> 15) * 64 + fi * 4];
          uint4 u1 = *(const uint4*)&H2[(size_t)(e1 >> 15) * 64 + fi * 4];
          uint4 u2 = *(const uint4*)&H2[(size_t)(e2 >> 15) * 64 + fi * 4];
          uint4 u3 = *(const uint4*)&H2[(size_t)(e3 >> 15) * 64 + fi * 4];
          float w0 = (float)(e0 & 0x7fffu) * dinv[e0 >> 15] * dcs;
          float w1 = (float)(e1 & 0x7fffu) * dinv[e1 >> 15] * dcs;
          float w2 = (float)(e2 & 0x7fffu) * dinv[e2 >> 15] * dcs;
          float w3 = (float)(e3 & 0x7fffu) * dinv[e3 >> 15] * dcs;
          a0 += w0 * bf_lo(u0.x); a1 += w0 * bf_hi(u0.x);
          a2 += w0 * bf_lo(u0.y); a3 += w0 * bf_hi(u0.y);
          a4 += w0 * bf_lo(u0.z); a5 += w0 * bf_hi(u0.z);
          a6 += w0 * bf_lo(u0.w); a7 += w0 * bf_hi(u0.w);
          a0 += w1 * bf_lo(u1.x); a1 += w1 * bf_hi(u1.x);
          a2 += w1 * bf_lo(u1.y); a3 += w1 * bf_hi(u1.y);
          a4 += w1 * bf_lo(u1.z); a5 += w1 * bf_hi(u1.z);
          a6 += w1 * bf_lo(u1.w); a7 += w1 * bf_hi(u1.w);
          a0 += w2 * bf_lo(u2.x); a1 += w2 * bf_hi(u2.x);
          a2 += w2 * bf_lo(u2.y); a3 += w2 * bf_hi(u2.y);
          a4 += w2 * bf_lo(u2.z); a5 += w2 * bf_hi(u2.z);
          a6 += w2 * bf_lo(u2.w); a7 += w2 * bf_hi(u2.w);
          a0 += w3 * bf_lo(u3.x); a1 += w3 * bf_hi(u3.x);
          a2 += w3 * bf_lo(u3.y); a3 += w3 * bf_hi(u3.y);
          a4 += w3 * bf_lo(u3.z); a5 += w3 * bf_hi(u3.z);
          a6 += w3 * bf_lo(u3.w); a7 += w3 * bf_hi(u3.w);
        }
        for (; i < iters; ++i) {
          unsigned e0 = __shfl(rec, 4 * i + q, 64);
          float w0 = (float)(e0 & 0x7fffu) * dinv[e0 >> 15] * dcs;
          uint4 u0 = *(const uint4*)&H2[(size_t)(e0 >> 15) * 64 + fi * 4];
          a0 += w0 * bf_lo(u0.x); a1 += w0 * bf_hi(u0.x);
          a2 += w0 * bf_lo(u0.y); a3 += w0 * bf_hi(u0.y);
          a4 += w0 * bf_lo(u0.z); a5 += w0 * bf_hi(u0.z);
          a6 += w0 * bf_lo(u0.w); a7 += w0 * bf_hi(u0.w);
        }
      }
      a0 += __shfl_xor(a0, 16, 64); a0 += __shfl_xor(a0, 32, 64);
      a1 += __shfl_xor(a1, 16, 64); a1 += __shfl_xor(a1, 32, 64);
      a2 += __shfl_xor(a2, 16, 64); a2 += __shfl_xor(a2, 32, 64);
      a3 += __shfl_xor(a3, 16, 64); a3 += __shfl_xor(a3, 32, 64);
      a4 += __shfl_xor(a4, 16, 64); a4 += __shfl_xor(a4, 32, 64);
      a5 += __shfl_xor(a5, 16, 64); a5 += __shfl_xor(a5, 32, 64);
      a6 += __shfl_xor(a6, 16, 64); a6 += __shfl_xor(a6, 32, 64);
      a7 += __shfl_xor(a7, 16, 64); a7 += __shfl_xor(a7, 32, 64);
      if (q == 0) {
        float sw = dv * dv;
        uint4 us = *(const uint4*)&H2[(size_t)c * 64 + fi * 4];
        a0 += sw * bf_lo(us.x); a1 += sw * bf_hi(us.x);
        a2 += sw * bf_lo(us.y); a3 += sw * bf_hi(us.y);
        a4 += sw * bf_lo(us.z); a5 += sw * bf_hi(us.z);
        a6 += sw * bf_lo(us.w); a7 += sw * bf_hi(us.w);
        uint4 o;
        o.x = bpack(a0, a1); o.y = bpack(a2, a3); o.z = bpack(a4, a5); o.w = bpack(a6, a7);
        *(uint4*)&sRow[row][fi * 8] = o;
      }
    } else if (q == 0) {
      uint4 z = make_uint4(0, 0, 0, 0);
      *(uint4*)&sRow[row][fi * 8] = z;   // keep LDS defined for guarded GEMM rows
    }
  }
  __syncthreads();

  // ---- stage 2: 16x128 GEMM from LDS (A rows = block's 16 nodes) ----
  int cl = fi;                  // A-row / B-col / D-col offset
  int kg = q;                   // k-group 0..3
  int cb0 = wave * 2;
  bf16x8 a[4];
  #pragma unroll
  for (int kt = 0; kt < 4; ++kt) a[kt] = *(const bf16x8*)&sRow[cl][kg * 8 + kt * 32];
  #pragma unroll
  for (int cc = 0; cc < 2; ++cc) {
    int colj = (cb0 + cc) * 16 + cl;
    const ushort_t* wh = Whi + (size_t)colj * D + kg * 8;
    const ushort_t* wl = Wlo + (size_t)colj * D + kg * 8;
    f32x4 acc = {0.f, 0.f, 0.f, 0.f};
    #pragma unroll
    for (int kt = 0; kt < 4; ++kt)
      acc = __builtin_amdgcn_mfma_f32_16x16x32_bf16(a[kt], *(const bf16x8*)(wh + kt * 32), acc, 0, 0, 0);
    #pragma unroll
    for (int kt = 0; kt < 4; ++kt)
      acc = __builtin_amdgcn_mfma_f32_16x16x32_bf16(a[kt], *(const bf16x8*)(wl + kt * 32), acc, 0, 0, 0);
    float bv = bias[colj];
    #pragma unroll
    for (int i = 0; i < 4; ++i) {
      int r = blk * 16 + kg * 4 + i;
      if (r < N) {
        float o = acc[i] + bv;
        if (TANH) {
          o = tanhf(o);
          ((ushort_t*)outv)[(size_t)r * D + colj] = bh16(o);
        } else {
          if (SKIP) o += __uint_as_float((unsigned)skipb[(size_t)r * D + colj] << 16);
          ((float*)outv)[(size_t)r * D + colj] = o;
        }
      }
    }
  }
}

// ---------------- launch ----------------
extern "C" void kernel_launch(void* const* d_in, const int* in_sizes, int n_in,
                              void* d_out, int out_size, void* d_ws, size_t ws_size,
                              hipStream_t stream) {
  const int*   et = (const int*)d_in[0];
  const float* ef = (const float*)d_in[1];
  const float* x  = (const float*)d_in[2];
  const float* W1 = (const float*)d_in[3];
  const float* b1 = (const float*)d_in[4];
  const float* W2 = (const float*)d_in[5];
  const float* b2 = (const float*)d_in[6];

  int E = in_sizes[1];
  int N = in_sizes[2] / D;
  const int* row = et;
  const int* col = et + E;

  int NB = (N + 127) >> 7;            // 782 buckets of 128 nodes
  int B1 = (E + EPB - 1) / EPB;       // 391 edge blocks (<= 512 for k_hscan)
  int B1pad = (B1 + 7) & ~7;

  char* p = (char*)d_ws;
  auto alloc = [&](size_t bytes) { char* q = p; p += (bytes + 255) & ~(size_t)255; return q; };
  int*      gh       = (int*)     alloc((size_t)NB * B1pad * 4);
  int*      binTotal = (int*)     alloc((size_t)NB * 4);
  ull*      a_e      = (ull*)     alloc((size_t)E * 8);   // packed (c<<15|q, r)
  unsigned* elist    = (unsigned*)alloc((size_t)E * 4);   // r<<15 | ew_q15, dest-sorted
  int*      offs     = (int*)     alloc((size_t)(N + 1) * 4);
  float*    dinv     = (float*)   alloc((size_t)N * 4);
  unsigned* xb       = (unsigned*)alloc((size_t)N * 64 * 4);   // bf16x2 [N,64], live till end (skip)
  unsigned* a1b      = (unsigned*)alloc((size_t)N * 64 * 4);   // a1 bf16x2 (in ws: layer-2 reads it while writing d_out)
  ushort_t* whi1 = (ushort_t*)alloc(D * D * 2);
  ushort_t* wlo1 = (ushort_t*)alloc(D * D * 2);
  ushort_t* whi2 = (ushort_t*)alloc(D * D * 2);
  ushort_t* wlo2 = (ushort_t*)alloc(D * D * 2);

  int prepBlocks = (N * 64 + 2 * D * D + 255) / 256;
  k_h1<<<B1 + prepBlocks, 256, 0, stream>>>(col, E, B1, B1pad, gh, NB,
                                            (const float2*)x, xb, N * 64,
                                            W1, W2, whi1, wlo1, whi2, wlo2);
  k_hscan<<<NB, 512, 0, stream>>>(gh, binTotal, B1, B1pad);
  k_scatter<<<B1, 256, 0, stream>>>(row, col, ef, gh, binTotal, B1pad, NB, a_e, E);
  k_bucket<<<NB, 256, 0, stream>>>(a_e, binTotal, offs, dinv, elist, N, E, NB);

  int fb = (N + 15) / 16;
  // layer 1 (fused): a1 = tanh((A~ @ xb) @ W1^T + b1) -> a1b (bf16, ws)
  k_aggmm<1, 0><<<fb, 256, 0, stream>>>(xb, elist, offs, dinv, whi1, wlo1, b1, nullptr, a1b, N);
  // layer 2 (fused): out = (A~ @ a1) @ W2^T + b2 + x(bf16 skip) -> d_out f32
  k_aggmm<0, 1><<<fb, 256, 0, stream>>>(a1b, elist, offs, dinv, whi2, wlo2, b2,
                                        (const ushort_t*)xb, d_out, N);
}

// Round 19
// 240.241 us; speedup vs baseline: 1.0749x; 1.0749x over previous
//
#include <hip/hip_runtime.h>
#include <math.h>

#define D 128
#define EPB 4096          // edges per block for hist/scatter
#define MAXNB 800         // LDS histogram capacity (NB = ceil(N/128) = 782)
#define BCAP 3072         // k_bucket LDS record capacity (mean bucket 2046, max ~2300)

typedef unsigned long long ull;
typedef unsigned short ushort_t;
typedef __attribute__((ext_vector_type(8))) short bf16x8;
typedef __attribute__((ext_vector_type(4))) float f32x4;

__device__ __forceinline__ float bf_lo(unsigned u) { return __uint_as_float(u << 16); }
__device__ __forceinline__ float bf_hi(unsigned u) { return __uint_as_float(u & 0xffff0000u); }
__device__ __forceinline__ unsigned bpack(float a, float b) {  // RNE bf16x2
  unsigned ua = __float_as_uint(a), ub = __float_as_uint(b);
  ua += 0x7fff + ((ua >> 16) & 1);
  ub += 0x7fff + ((ub >> 16) & 1);
  return (ua >> 16) | (ub & 0xffff0000u);
}
__device__ __forceinline__ ushort_t bh16(float a) {  // RNE bf16
  unsigned ua = __float_as_uint(a);
  ua += 0x7fff + ((ua >> 16) & 1);
  return (ushort_t)(ua >> 16);
}

// ---- hist level-1 (col>>7) with LDS atomics; prep (x cast + W bf16 hi/lo split) in tail blocks ----
__global__ __launch_bounds__(256) void k_h1(const int* __restrict__ col, int E, int B1, int B1pad,
                                            int* __restrict__ gh, int NB,
                                            const float2* __restrict__ x2, unsigned* __restrict__ xb, int n64,
                                            const float* __restrict__ W1, const float* __restrict__ W2,
                                            ushort_t* __restrict__ Whi1, ushort_t* __restrict__ Wlo1,
                                            ushort_t* __restrict__ Whi2, ushort_t* __restrict__ Wlo2) {
  int b = blockIdx.x, t = threadIdx.x;
  if (b < B1) {
    __shared__ int h[MAXNB];
    for (int i = t; i < NB; i += 256) h[i] = 0;
    __syncthreads();
    int e0 = b * EPB, e1 = min(E, e0 + EPB);
    for (int e = e0 + t; e < e1; e += 256) atomicAdd(&h[col[e] >> 7], 1);
    __syncthreads();
    for (int i = t; i < NB; i += 256) gh[i * B1pad + b] = h[i];
    return;
  }
  int idx = (b - B1) * 256 + t;
  if (idx < n64) { float2 v = x2[idx]; xb[idx] = bpack(v.x, v.y); return; }
  int j = idx - n64;
  if (j >= 2 * D * D) return;
  const float* W = (j < D * D) ? W1 : W2;
  ushort_t* Hh = (j < D * D) ? Whi1 : Whi2;
  ushort_t* Hl = (j < D * D) ? Wlo1 : Wlo2;
  int k = j & (D * D - 1);
  float w = W[k];
  ushort_t hh = bh16(w);
  Hh[k] = hh;
  Hl[k] = bh16(w - __uint_as_float((unsigned)hh << 16));
}

// ---- per-bin scan across blocks (B1 <= 512): gh[bin][b] -> excl prefix; binTotal[bin] = sum ----
__global__ __launch_bounds__(512) void k_hscan(int* __restrict__ gh, int* __restrict__ binTotal,
                                               int B1, int B1pad) {
  __shared__ int wsum[8];
  int bin = blockIdx.x, t = threadIdx.x;
  int v = (t < B1) ? gh[bin * B1pad + t] : 0;
  int lane = t & 63, wid = t >> 6;
  int x = v;
  #pragma unroll
  for (int d = 1; d < 64; d <<= 1) { int y = __shfl_up(x, d, 64); if (lane >= d) x += y; }
  if (lane == 63) wsum[wid] = x;
  __syncthreads();
  int woff = 0;
  for (int w = 0; w < wid; ++w) woff += wsum[w];
  if (t < B1) gh[bin * B1pad + t] = woff + x - v;
  if (t == 511) binTotal[bin] = woff + x;   // last lane of last wave: inclusive total
}

// ---------------- block exclusive scan helper (256 threads) ----------------
__device__ __forceinline__ int block_excl_scan(int v, int t, int* wsum, int* total) {
  int lane = t & 63, wid = t >> 6;
  int x = v;
  #pragma unroll
  for (int d = 1; d < 64; d <<= 1) {
    int y = __shfl_up(x, d, 64);
    if (lane >= d) x += y;
  }
  if (lane == 63) wsum[wid] = x;
  __syncthreads();
  int woff = 0;
  for (int w = 0; w < wid; ++w) woff += wsum[w];
  if (total) { int tot = 0; for (int w = 0; w < 4; ++w) tot += wsum[w]; *total = tot; }
  return woff + x - v;
}

// ---- scatter: LDS counting-sort per block, coalesced packed-ull output ----
__global__ __launch_bounds__(256) void k_scatter(const int* __restrict__ row, const int* __restrict__ col,
                                                 const float* __restrict__ ew,
                                                 const int* __restrict__ gh, const int* __restrict__ binTotal,
                                                 int B1pad, int NB,
                                                 ull* __restrict__ a_e, int E) {
  __shared__ ull recs[EPB];
  __shared__ int hist[MAXNB];   // becomes exclusive pfx in place
  __shared__ int cur[MAXNB];
  __shared__ int wb[MAXNB];
  __shared__ int bbase[MAXNB];
  __shared__ int wsum[4];
  int b = blockIdx.x, t = threadIdx.x;
  for (int i = t; i < NB; i += 256) { hist[i] = 0; cur[i] = 0; }
  __syncthreads();
  int e0 = b * EPB;
  int cnt = min(E - e0, EPB);
  ull v[16];
  #pragma unroll
  for (int k = 0; k < 16; ++k) {
    int idx = t + k * 256;
    v[k] = 0;
    if (idx < cnt) {
      int e = e0 + idx;
      int c = col[e];
      unsigned q = __float2uint_rn(ew[e] * 32767.0f);
      if (q > 32767u) q = 32767u;
      unsigned hi = ((unsigned)c << 15) | q;
      v[k] = ((ull)hi << 32) | (unsigned)row[e];
      atomicAdd(&hist[hi >> 22], 1);
    }
  }
  __syncthreads();
  int base = t * 4;
  // scan #A: binTotal -> bbase (exclusive bin bases)
  int bt[4]; int sb = 0;
  #pragma unroll
  for (int u = 0; u < 4; ++u) { bt[u] = (base + u < NB) ? binTotal[base + u] : 0; sb += bt[u]; }
  int exb = block_excl_scan(sb, t, wsum, nullptr);
  {
    int run = exb;
    #pragma unroll
    for (int u = 0; u < 4; ++u) { if (base + u < NB) bbase[base + u] = run; run += bt[u]; }
  }
  __syncthreads();
  // scan #B: hist -> exclusive pfx in place; wb = bbase + gh - pfx
  int hv[4];
  #pragma unroll
  for (int u = 0; u < 4; ++u) hv[u] = (base + u < NB) ? hist[base + u] : 0;
  int s = hv[0] + hv[1] + hv[2] + hv[3];
  int excl = block_excl_scan(s, t, wsum, nullptr);
  int run = excl;
  #pragma unroll
  for (int u = 0; u < 4; ++u) {
    if (base + u < NB) {
      hist[base + u] = run;
      wb[base + u] = bbase[base + u] + gh[(base + u) * B1pad + b] - run;
    }
    run += hv[u];
  }
  __syncthreads();
  #pragma unroll
  for (int k = 0; k < 16; ++k) {
    if (t + k * 256 < cnt) {
      unsigned bkt = (unsigned)(v[k] >> 54);
      int idx = hist[bkt] + atomicAdd(&cur[bkt], 1);
      recs[idx] = v[k];
    }
  }
  __syncthreads();
  for (int i = t; i < cnt; i += 256) {
    ull r = recs[i];
    a_e[wb[(unsigned)(r >> 54)] + i] = r;
  }
}

// ---- level-2: per-bucket 128-bin counting sort; LDS-staged (read a_e once, coalesced writes) ----
__global__ __launch_bounds__(256) void k_bucket(const ull* __restrict__ a_e,
                                                const int* __restrict__ binTotal,
                                                int* __restrict__ offs, float* __restrict__ dinv,
                                                unsigned* __restrict__ sorted2, int N, int E, int NB) {
  __shared__ ull recLds[BCAP];
  __shared__ unsigned sortLds[BCAP];
  __shared__ int hist[128];
  __shared__ float wdeg[128];
  __shared__ int pfx[128];
  __shared__ int cur[128];
  __shared__ int wred[4];
  __shared__ int s0sh;
  int bin = blockIdx.x, t = threadIdx.x;
  if (t < 128) { hist[t] = 0; wdeg[t] = 0.f; cur[t] = 0; }
  // masked block-reduce: s0 = sum_{j<bin} binTotal[j]
  int part = 0;
  for (int j = t; j < NB; j += 256) if (j < bin) part += binTotal[j];
  #pragma unroll
  for (int d = 32; d >= 1; d >>= 1) part += __shfl_xor(part, d, 64);
  if ((t & 63) == 0) wred[t >> 6] = part;
  __syncthreads();
  if (t == 0) s0sh = wred[0] + wred[1] + wred[2] + wred[3];
  if (t == 0 && bin == 0) offs[N] = E;
  __syncthreads();
  int s0 = s0sh;
  int cnt = binTotal[bin];
  int fits = (cnt <= BCAP);
  if (fits) {
    for (int i = t; i < cnt; i += 256) recLds[i] = a_e[s0 + i];
    __syncthreads();
  }
  for (int i = t; i < cnt; i += 256) {
    unsigned hi = (unsigned)((fits ? recLds[i] : a_e[s0 + i]) >> 32);
    int lc = (hi >> 15) & 127;
    atomicAdd(&hist[lc], 1);
    atomicAdd(&wdeg[lc], (float)(hi & 32767u) * (1.0f / 32767.0f));
  }
  __syncthreads();
  if (t == 0) { int run = 0; for (int i = 0; i < 128; ++i) { pfx[i] = run; run += hist[i]; } }
  __syncthreads();
  int c0 = bin << 7;
  if (t < 128 && c0 + t < N) {
    offs[c0 + t] = s0 + pfx[t];
    dinv[c0 + t] = rsqrtf(wdeg[t] + 1.0f);
  }
  for (int i = t; i < cnt; i += 256) {
    ull v = fits ? recLds[i] : a_e[s0 + i];
    unsigned hi = (unsigned)(v >> 32);
    int lc = (hi >> 15) & 127;
    int pos = pfx[lc] + atomicAdd(&cur[lc], 1);
    unsigned sv = ((unsigned)v << 15) | (hi & 32767u);   // r<<15 | ew_q15
    if (fits) sortLds[pos] = sv; else sorted2[s0 + pos] = sv;
  }
  if (fits) {
    __syncthreads();
    for (int i = t; i < cnt; i += 256) sorted2[s0 + i] = sortLds[i];   // coalesced
  }
}

// ---- gather-aggregate (R8-proven structure): wave per node, 4 edge slots x 16 lanes, 4-deep ----
// norm decoded on the fly: w = ew_q15 * dinv[r] * (dinv[c]/32767)
__global__ __launch_bounds__(256) void k_agg(const unsigned* __restrict__ H2,
                                             const unsigned* __restrict__ elist,
                                             const int* __restrict__ offs, const float* __restrict__ dinv,
                                             unsigned* __restrict__ outb, int N) {
  int lane = threadIdx.x & 63;
  int c = blockIdx.x * 4 + (threadIdx.x >> 6);
  if (c >= N) return;
  int start = offs[c];
  int m = offs[c + 1] - start;
  int q = lane >> 4;            // edge slot 0..3
  int fi = lane & 15;           // uint4 index within row (features fi*8..fi*8+7)
  float dv = dinv[c];
  float dcs = dv * (1.0f / 32767.0f);
  float a0 = 0.f, a1 = 0.f, a2 = 0.f, a3 = 0.f, a4 = 0.f, a5 = 0.f, a6 = 0.f, a7 = 0.f;
  for (int base = 0; base < m; base += 64) {
    int chunk = min(64, m - base);
    unsigned rec = (lane < chunk) ? elist[start + base + lane] : 0u;  // pad: row0, w=0
    int iters = (chunk + 3) >> 2;
    int i = 0;
    for (; i + 4 <= iters; i += 4) {
      unsigned e0 = __shfl(rec, 4 * i + q, 64);
      unsigned e1 = __shfl(rec, 4 * i + 4 + q, 64);
      unsigned e2 = __shfl(rec, 4 * i + 8 + q, 64);
      unsigned e3 = __shfl(rec, 4 * i + 12 + q, 64);
      uint4 u0 = *(const uint4*)&H2[(size_t)(e0 >> 15) * 64 + fi * 4];
      uint4 u1 = *(const uint4*)&H2[(size_t)(e1 >> 15) * 64 + fi * 4];
      uint4 u2 = *(const uint4*)&H2[(size_t)(e2 >> 15) * 64 + fi * 4];
      uint4 u3 = *(const uint4*)&H2[(size_t)(e3 >> 15) * 64 + fi * 4];
      float w0 = (float)(e0 & 0x7fffu) * dinv[e0 >> 15] * dcs;
      float w1 = (float)(e1 & 0x7fffu) * dinv[e1 >> 15] * dcs;
      float w2 = (float)(e2 & 0x7fffu) * dinv[e2 >> 15] * dcs;
      float w3 = (float)(e3 & 0x7fffu) * dinv[e3 >> 15] * dcs;
      a0 += w0 * bf_lo(u0.x); a1 += w0 * bf_hi(u0.x);
      a2 += w0 * bf_lo(u0.y); a3 += w0 * bf_hi(u0.y);
      a4 += w0 * bf_lo(u0.z); a5 += w0 * bf_hi(u0.z);
      a6 += w0 * bf_lo(u0.w); a7 += w0 * bf_hi(u0.w);
      a0 += w1 * bf_lo(u1.x); a1 += w1 * bf_hi(u1.x);
      a2 += w1 * bf_lo(u1.y); a3 += w1 * bf_hi(u1.y);
      a4 += w1 * bf_lo(u1.z); a5 += w1 * bf_hi(u1.z);
      a6 += w1 * bf_lo(u1.w); a7 += w1 * bf_hi(u1.w);
      a0 += w2 * bf_lo(u2.x); a1 += w2 * bf_hi(u2.x);
      a2 += w2 * bf_lo(u2.y); a3 += w2 * bf_hi(u2.y);
      a4 += w2 * bf_lo(u2.z); a5 += w2 * bf_hi(u2.z);
      a6 += w2 * bf_lo(u2.w); a7 += w2 * bf_hi(u2.w);
      a0 += w3 * bf_lo(u3.x); a1 += w3 * bf_hi(u3.x);
      a2 += w3 * bf_lo(u3.y); a3 += w3 * bf_hi(u3.y);
      a4 += w3 * bf_lo(u3.z); a5 += w3 * bf_hi(u3.z);
      a6 += w3 * bf_lo(u3.w); a7 += w3 * bf_hi(u3.w);
    }
    for (; i < iters; ++i) {
      unsigned e0 = __shfl(rec, 4 * i + q, 64);
      float w0 = (float)(e0 & 0x7fffu) * dinv[e0 >> 15] * dcs;
      uint4 u0 = *(const uint4*)&H2[(size_t)(e0 >> 15) * 64 + fi * 4];
      a0 += w0 * bf_lo(u0.x); a1 += w0 * bf_hi(u0.x);
      a2 += w0 * bf_lo(u0.y); a3 += w0 * bf_hi(u0.y);
      a4 += w0 * bf_lo(u0.z); a5 += w0 * bf_hi(u0.z);
      a6 += w0 * bf_lo(u0.w); a7 += w0 * bf_hi(u0.w);
    }
  }
  a0 += __shfl_xor(a0, 16, 64); a0 += __shfl_xor(a0, 32, 64);
  a1 += __shfl_xor(a1, 16, 64); a1 += __shfl_xor(a1, 32, 64);
  a2 += __shfl_xor(a2, 16, 64); a2 += __shfl_xor(a2, 32, 64);
  a3 += __shfl_xor(a3, 16, 64); a3 += __shfl_xor(a3, 32, 64);
  a4 += __shfl_xor(a4, 16, 64); a4 += __shfl_xor(a4, 32, 64);
  a5 += __shfl_xor(a5, 16, 64); a5 += __shfl_xor(a5, 32, 64);
  a6 += __shfl_xor(a6, 16, 64); a6 += __shfl_xor(a6, 32, 64);
  a7 += __shfl_xor(a7, 16, 64); a7 += __shfl_xor(a7, 32, 64);
  if (q == 0) {
    float sw = dv * dv;
    uint4 us = *(const uint4*)&H2[(size_t)c * 64 + fi * 4];
    a0 += sw * bf_lo(us.x); a1 += sw * bf_hi(us.x);
    a2 += sw * bf_lo(us.y); a3 += sw * bf_hi(us.y);
    a4 += sw * bf_lo(us.z); a5 += sw * bf_hi(us.z);
    a6 += sw * bf_lo(us.w); a7 += sw * bf_hi(us.w);
    uint4 o;
    o.x = bpack(a0, a1); o.y = bpack(a2, a3); o.z = bpack(a4, a5); o.w = bpack(a6, a7);
    *(uint4*)&outb[(size_t)c * 64 + fi * 4] = o;
  }
}

// ---- MFMA GEMM (bf16 hi+lo W): B in registers, rows streamed ----
// TANH: out bf16 (out-of-place). else: out f32 with bf16 skip.
template<int TANH, int SKIP>
__global__ __launch_bounds__(256) void k_mgemm(const ushort_t* __restrict__ S,
                                               const ushort_t* __restrict__ Whi,
                                               const ushort_t* __restrict__ Wlo,
                                               const float* __restrict__ bias,
                                               const ushort_t* __restrict__ skipb,
                                               void* __restrict__ outv, int n) {
  int wave = threadIdx.x >> 6, lane = threadIdx.x & 63;
  int cl = lane & 15;
  int kg = lane >> 4;
  int cb0 = wave * 2;

  bf16x8 bh[2][4], bl[2][4];
  float bv[2];
  #pragma unroll
  for (int c = 0; c < 2; ++c) {
    int col = (cb0 + c) * 16 + cl;
    const ushort_t* wh = Whi + (size_t)col * D + kg * 8;
    const ushort_t* wl = Wlo + (size_t)col * D + kg * 8;
    #pragma unroll
    for (int kt = 0; kt < 4; ++kt) {
      bh[c][kt] = *(const bf16x8*)(wh + kt * 32);
      bl[c][kt] = *(const bf16x8*)(wl + kt * 32);
    }
    bv[c] = bias[col];
  }

  int ntiles = (n + 15) >> 4;
  for (int t = blockIdx.x; t < ntiles; t += gridDim.x) {
    int arow = t * 16 + cl; if (arow >= n) arow = n - 1;
    const ushort_t* srow = S + (size_t)arow * D + kg * 8;
    bf16x8 a[4];
    #pragma unroll
    for (int kt = 0; kt < 4; ++kt) a[kt] = *(const bf16x8*)(srow + kt * 32);
    #pragma unroll
    for (int c = 0; c < 2; ++c) {
      f32x4 acc = {0.f, 0.f, 0.f, 0.f};
      #pragma unroll
      for (int kt = 0; kt < 4; ++kt)
        acc = __builtin_amdgcn_mfma_f32_16x16x32_bf16(a[kt], bh[c][kt], acc, 0, 0, 0);
      #pragma unroll
      for (int kt = 0; kt < 4; ++kt)
        acc = __builtin_amdgcn_mfma_f32_16x16x32_bf16(a[kt], bl[c][kt], acc, 0, 0, 0);
      int col = (cb0 + c) * 16 + cl;
      #pragma unroll
      for (int i = 0; i < 4; ++i) {
        int r = t * 16 + kg * 4 + i;
        if (r < n) {
          float o = acc[i] + bv[c];
          if (TANH) {
            o = tanhf(o);
            ((ushort_t*)outv)[(size_t)r * D + col] = bh16(o);
          } else {
            if (SKIP) o += __uint_as_float((unsigned)skipb[(size_t)r * D + col] << 16);
            ((float*)outv)[(size_t)r * D + col] = o;
          }
        }
      }
    }
  }
}

// ---------------- launch ----------------
extern "C" void kernel_launch(void* const* d_in, const int* in_sizes, int n_in,
                              void* d_out, int out_size, void* d_ws, size_t ws_size,
                              hipStream_t stream) {
  const int*   et = (const int*)d_in[0];
  const float* ef = (const float*)d_in[1];
  const float* x  = (const float*)d_in[2];
  const float* W1 = (const float*)d_in[3];
  const float* b1 = (const float*)d_in[4];
  const float* W2 = (const float*)d_in[5];
  const float* b2 = (const float*)d_in[6];

  int E = in_sizes[1];
  int N = in_sizes[2] / D;
  const int* row = et;
  const int* col = et + E;

  int NB = (N + 127) >> 7;            // 782 buckets of 128 nodes
  int B1 = (E + EPB - 1) / EPB;       // 391 edge blocks (<= 512 for k_hscan)
  int B1pad = (B1 + 7) & ~7;

  char* p = (char*)d_ws;
  auto alloc = [&](size_t bytes) { char* q = p; p += (bytes + 255) & ~(size_t)255; return q; };
  int*      gh       = (int*)     alloc((size_t)NB * B1pad * 4);
  int*      binTotal = (int*)     alloc((size_t)NB * 4);
  ull*      a_e      = (ull*)     alloc((size_t)E * 8);   // packed (c<<15|q, r)
  unsigned* elist    = (unsigned*)alloc((size_t)E * 4);   // r<<15 | ew_q15, dest-sorted
  int*      offs     = (int*)     alloc((size_t)(N + 1) * 4);
  float*    dinv     = (float*)   alloc((size_t)N * 4);
  unsigned* xb       = (unsigned*)alloc((size_t)N * 64 * 4);   // bf16x2 [N,64], live till end (skip)
  unsigned* s2b      = (unsigned*)alloc((size_t)N * 64 * 4);   // s2 bf16x2
  ushort_t* whi1 = (ushort_t*)alloc(D * D * 2);
  ushort_t* wlo1 = (ushort_t*)alloc(D * D * 2);
  ushort_t* whi2 = (ushort_t*)alloc(D * D * 2);
  ushort_t* wlo2 = (ushort_t*)alloc(D * D * 2);
  // d_out (f32 [N,128]) double-buffers layer-1 activations:
  //   lower half: s1 (agg1 out) ; upper half: a1 (mgemm1 out) -- mgemm1 OUT-OF-PLACE (race-free)
  unsigned* s1b = (unsigned*)d_out;
  unsigned* a1b = s1b + (size_t)N * 64;

  int prepBlocks = (N * 64 + 2 * D * D + 255) / 256;
  k_h1<<<B1 + prepBlocks, 256, 0, stream>>>(col, E, B1, B1pad, gh, NB,
                                            (const float2*)x, xb, N * 64,
                                            W1, W2, whi1, wlo1, whi2, wlo2);
  k_hscan<<<NB, 512, 0, stream>>>(gh, binTotal, B1, B1pad);
  k_scatter<<<B1, 256, 0, stream>>>(row, col, ef, gh, binTotal, B1pad, NB, a_e, E);
  k_bucket<<<NB, 256, 0, stream>>>(a_e, binTotal, offs, dinv, elist, N, E, NB);

  int ab = (N + 3) / 4;
  int gb = 1024;
  // layer 1: s1 = A~ @ xb -> s1b (d_out lower) ; a1 = tanh(s1@W1^T + b1) -> a1b (d_out upper)
  k_agg<<<ab, 256, 0, stream>>>(xb, elist, offs, dinv, s1b, N);
  k_mgemm<1, 0><<<gb, 256, 0, stream>>>((const ushort_t*)s1b, whi1, wlo1, b1, nullptr, a1b, N);
  // layer 2: s2 = A~ @ a1 -> s2b ; out = s2@W2^T + b2 + xb(bf16 skip) -> d_out f32
  k_agg<<<ab, 256, 0, stream>>>(a1b, elist, offs, dinv, s2b, N);
  k_mgemm<0, 1><<<gb, 256, 0, stream>>>((const ushort_t*)s2b, whi2, wlo2, b2,
                                        (const ushort_t*)xb, d_out, N);
}